// Round 1
// 1193.176 us; speedup vs baseline: 1.1854x; 1.1854x over previous
//
#include <hip/hip_runtime.h>
#include <hip/hip_bf16.h>
#include <stdint.h>

#define B_   4
#define C_   256
#define HW_  65536
#define NH_  8
#define HD_  32
#define G_   32
#define CPG_ 8

typedef __bf16 bf16x8 __attribute__((ext_vector_type(8)));
typedef float  f32x4  __attribute__((ext_vector_type(4)));

__device__ __forceinline__ unsigned short f2bf(float f) {
  union { float f; unsigned u; } v; v.f = f;
  unsigned r = v.u + 0x7fffu + ((v.u >> 16) & 1u);
  return (unsigned short)(r >> 16);
}

#define GL16(gp, lp) __builtin_amdgcn_global_load_lds( \
    (const __attribute__((address_space(1))) void*)(gp), \
    (__attribute__((address_space(3))) void*)(lp), 16, 0, 0)

// Pixel permutation: all intermediate tensors use window-token pixel order
//   n' = ((hp*32 + wp) << 6) + (h&7)*8 + (w&7),  window = n'>>6, token = n'&63
// so each (b, channel, window) is 64 contiguous bf16 = 128B in qkv/xn/attn.
// conv1x1 GEMMs are pixel-order oblivious; only norm_transpose (producer) and
// oproj_gemm (final un-permute) touch the mapping.

// ---------------- K1: groupnorm partial sums ----------------
__global__ void gn_partial(const float* __restrict__ x, float* __restrict__ part) {
  int chunk = blockIdx.x, g = blockIdx.y, b = blockIdx.z;
  const float* p = x + ((size_t)b * C_ + g * CPG_) * HW_ + (size_t)chunk * 65536;
  int t = threadIdx.x;
  float s1 = 0.f, s2 = 0.f;
  for (int it = 0; it < 64; ++it) {
    float4 v = reinterpret_cast<const float4*>(p)[it * 256 + t];
    s1 += v.x + v.y + v.z + v.w;
    s2 += v.x * v.x + v.y * v.y + v.z * v.z + v.w * v.w;
  }
  for (int off = 32; off; off >>= 1) {
    s1 += __shfl_xor(s1, off, 64);
    s2 += __shfl_xor(s2, off, 64);
  }
  __shared__ float ls1[4], ls2[4];
  int wv = t >> 6;
  if ((t & 63) == 0) { ls1[wv] = s1; ls2[wv] = s2; }
  __syncthreads();
  if (t == 0) {
    float a = ls1[0] + ls1[1] + ls1[2] + ls1[3];
    float c = ls2[0] + ls2[1] + ls2[2] + ls2[3];
    int gi = (b * G_ + g) * 8 + chunk;
    part[gi * 2] = a; part[gi * 2 + 1] = c;
  }
}

// ---------------- K2a: finalize stats -> per (b,c) affine ----------------
__global__ void gn_finalize(const float* __restrict__ part,
                            const float* __restrict__ gn_w, const float* __restrict__ gn_b,
                            float* __restrict__ A, float* __restrict__ D) {
  int b = blockIdx.x, c = threadIdx.x;
  int g = c >> 3;
  float s1 = 0.f, s2 = 0.f;
  for (int k = 0; k < 8; ++k) {
    s1 += part[((b * G_ + g) * 8 + k) * 2];
    s2 += part[((b * G_ + g) * 8 + k) * 2 + 1];
  }
  const float invN = 1.0f / (float)(CPG_ * HW_);
  float mu = s1 * invN;
  float var = s2 * invN - mu * mu;
  float rstd = rsqrtf(var + 1e-6f);
  float a = rstd * gn_w[c];
  A[b * C_ + c] = a;
  D[b * C_ + c] = gn_b[c] - mu * a;
}

// ---------------- K2b: pack weights to bf16 ----------------
__global__ void pack_weights(const float* __restrict__ qw, const float* __restrict__ kw,
                             const float* __restrict__ vw, const float* __restrict__ ow,
                             unsigned short* __restrict__ Wall, unsigned short* __restrict__ Wo) {
  int idx = blockIdx.x * 256 + threadIdx.x;   // 0..262143
  if (idx < 196608) {
    int o = idx >> 8, c = idx & 255;
    float v = (o < 256) ? qw[o * 256 + c]
            : (o < 512) ? kw[(o - 256) * 256 + c]
                        : vw[(o - 512) * 256 + c];
    Wall[idx] = f2bf(v);
  } else {
    int j = idx - 196608;
    Wo[j] = f2bf(ow[j]);
  }
}

// ---------------- K3: normalize + transpose CHW -> [n'][C] bf16 ----------------
__global__ void norm_transpose(const float* __restrict__ x, const float* __restrict__ A,
                               const float* __restrict__ D, unsigned short* __restrict__ xn) {
  __shared__ float Ts[64][65];
  __shared__ float As[64], Ds[64];
  int hw0 = blockIdx.x * 64, c0 = blockIdx.y * 64, b = blockIdx.z;
  int t = threadIdx.x;
  if (t < 64) { As[t] = A[b * C_ + c0 + t]; Ds[t] = D[b * C_ + c0 + t]; }
  const float* xb = x + (size_t)b * C_ * HW_;
  for (int it = 0; it < 4; ++it) {
    int idx = it * 256 + t;
    int ch = idx >> 4, p4 = idx & 15;
    float4 v = *reinterpret_cast<const float4*>(xb + (size_t)(c0 + ch) * HW_ + hw0 + p4 * 4);
    Ts[ch][p4 * 4 + 0] = v.x; Ts[ch][p4 * 4 + 1] = v.y;
    Ts[ch][p4 * 4 + 2] = v.z; Ts[ch][p4 * 4 + 3] = v.w;
  }
  __syncthreads();
  // block covers one image row h, columns w0..w0+63 (8 windows' same row)
  int h = hw0 >> 8, w0 = hw0 & 255;
  int nbase = ((h >> 3) * 32) * 64 + ((h & 7) * 8);
  unsigned short* outb = xn + (size_t)b * HW_ * C_ + c0;
  for (int it = 0; it < 2; ++it) {
    int idx = it * 256 + t;          // 0..511
    int px = idx >> 3, ck = (idx & 7) * 8;
    union { uint4 u; unsigned short s[8]; } tmp;
    for (int j = 0; j < 8; ++j) {
      float v = Ts[ck + j][px] * As[ck + j] + Ds[ck + j];
      tmp.s[j] = f2bf(v);
    }
    int w = w0 + px;
    int np = nbase + ((w >> 3) << 6) + (w & 7);   // window-token pixel index
    *reinterpret_cast<uint4*>(outb + (size_t)np * C_ + ck) = tmp.u;
  }
}

// ---------------- K4: QKV GEMM (m97-style 128x128, BK=32) ----------------
// Operates on permuted pixel index n' transparently (xn rows already permuted).
__global__ __launch_bounds__(256, 2) void qkv_gemm(
    const unsigned short* __restrict__ Wall, const unsigned short* __restrict__ xn,
    const float* __restrict__ qb, const float* __restrict__ kb, const float* __restrict__ vb,
    unsigned short* __restrict__ qkv) {
  __shared__ __align__(16) unsigned short As[128 * 32];
  __shared__ __align__(16) unsigned short Bs[128 * 32];
  int mt = blockIdx.x, nt = blockIdx.y, b = blockIdx.z;
  int m0 = mt * 128, n0 = nt * 128;
  int t = threadIdx.x;
  int wv = t >> 6, lane = t & 63;
  int lanelo = lane & 15, quad = lane >> 4;
  const unsigned short* xb = xn + (size_t)b * HW_ * C_;   // [n'][k], K=256
  f32x4 acc[4][4];
  for (int i = 0; i < 4; ++i)
    for (int j = 0; j < 4; ++j) acc[i][j] = f32x4{0.f, 0.f, 0.f, 0.f};
  int row_in = lane >> 2;
  int kcol = (lane & 3) * 8;
  int wm = wv & 1, wn = wv >> 1;
  for (int kt = 0; kt < 8; ++kt) {
    int k0 = kt * 32;
    for (int j = 0; j < 2; ++j) {
      int r = wv * 32 + j * 16 + row_in;
      GL16(Wall + (size_t)(m0 + r) * 256 + k0 + kcol, &As[(wv * 2 + j) * 512]);
      GL16(xb + (size_t)(n0 + r) * 256 + k0 + kcol, &Bs[(wv * 2 + j) * 512]);
    }
    __syncthreads();
    bf16x8 af[4], bff[4];
    for (int i = 0; i < 4; ++i) {
      af[i]  = *reinterpret_cast<const bf16x8*>(&As[(wm * 64 + i * 16 + lanelo) * 32 + quad * 8]);
      bff[i] = *reinterpret_cast<const bf16x8*>(&Bs[(wn * 64 + i * 16 + lanelo) * 32 + quad * 8]);
    }
    for (int i = 0; i < 4; ++i)
      for (int j = 0; j < 4; ++j)
        acc[i][j] = __builtin_amdgcn_mfma_f32_16x16x32_bf16(af[i], bff[j], acc[i][j], 0, 0, 0);
    __syncthreads();
  }
  for (int i = 0; i < 4; ++i) {
    int o_base = m0 + wm * 64 + i * 16 + quad * 4;
    for (int j = 0; j < 4; ++j) {
      int n = n0 + wn * 64 + j * 16 + lanelo;
      for (int r = 0; r < 4; ++r) {
        int o = o_base + r;
        float bias = (o < 256) ? qb[o] : (o < 512) ? kb[o - 256] : vb[o - 512];
        qkv[((size_t)b * 768 + o) * HW_ + n] = f2bf(acc[i][j][r] + bias);
      }
    }
  }
}

// ---------------- K5: windowed attention, 1 wave per (b,head,window) ----------------
// qkv layout [b][768][n'] => per (channel, window) 64 tokens are 128B contiguous.
__global__ __launch_bounds__(64) void attn_kernel(const unsigned short* __restrict__ qkv,
                                                  unsigned short* __restrict__ attn) {
  __shared__ __align__(16) unsigned short Qs[64 * 40];
  __shared__ __align__(16) unsigned short Ks[64 * 40];
  __shared__ __align__(16) unsigned short Vt[32 * 72];
  __shared__ __align__(16) unsigned short Ps[16 * 72];
  __shared__ __align__(16) unsigned short Os[16 * 40];
  int idx = blockIdx.x;
  int win = idx & 1023, head = (idx >> 10) & 7, b = idx >> 13;
  int lane = threadIdx.x;
  int lanelo = lane & 15, quad = lane >> 4;
  size_t base = ((size_t)b * 768 + head * 32) * HW_ + (size_t)win * 64;
  // Stage: each lane loads 8 contiguous tokens of one d => 128B runs per d.
  // Qs/Ks store with XOR-swizzled 16B column group (it ^ (m&3)) to break the
  // 8-way bank conflict of the 2B scatter (token stride 8*80B == 0 mod 128B).
  for (int it = 0; it < 4; ++it) {
    int id = it * 64 + lane;            // 0..255
    int d = id >> 3, m = id & 7;
    int t8 = m * 8;
    size_t goff = (size_t)d * HW_ + t8;
    union { uint4 u; unsigned short s[8]; } q, k, v;
    q.u = *reinterpret_cast<const uint4*>(qkv + base + goff);
    k.u = *reinterpret_cast<const uint4*>(qkv + base + (size_t)256 * HW_ + goff);
    v.u = *reinterpret_cast<const uint4*>(qkv + base + (size_t)512 * HW_ + goff);
    int col = ((it ^ (m & 3)) << 3) | (d & 7);
    for (int j = 0; j < 8; ++j) {
      Qs[(t8 + j) * 40 + col] = q.s[j];
      Ks[(t8 + j) * 40 + col] = k.s[j];
    }
    *reinterpret_cast<uint4*>(&Vt[d * 72 + t8]) = v.u;
  }
  __syncthreads();
  bf16x8 kf[4], vf0[2], vf1[2];
  for (int ni = 0; ni < 4; ++ni) {
    int row = ni * 16 + lanelo;
    int g = quad ^ ((row >> 3) & 3);
    kf[ni] = *reinterpret_cast<const bf16x8*>(&Ks[row * 40 + g * 8]);
  }
  for (int n2 = 0; n2 < 2; ++n2) {
    vf0[n2] = *reinterpret_cast<const bf16x8*>(&Vt[(n2 * 16 + lanelo) * 72 + quad * 8]);
    vf1[n2] = *reinterpret_cast<const bf16x8*>(&Vt[(n2 * 16 + lanelo) * 72 + 32 + quad * 8]);
  }
  const float scale = 0.17677669529663687f;
  const f32x4 zero = {0.f, 0.f, 0.f, 0.f};
  unsigned short* attb = attn + ((size_t)b * HW_ + (size_t)win * 64) * C_ + head * 32;
  for (int mi = 0; mi < 4; ++mi) {
    bf16x8 qf;
    {
      int row = mi * 16 + lanelo;
      int g = quad ^ ((row >> 3) & 3);
      qf = *reinterpret_cast<const bf16x8*>(&Qs[row * 40 + g * 8]);
    }
    f32x4 s[4];
    for (int ni = 0; ni < 4; ++ni)
      s[ni] = __builtin_amdgcn_mfma_f32_16x16x32_bf16(qf, kf[ni], zero, 0, 0, 0);
    for (int r = 0; r < 4; ++r) {
      float mx = fmaxf(fmaxf(s[0][r], s[1][r]), fmaxf(s[2][r], s[3][r])) * scale;
      for (int off = 1; off < 16; off <<= 1) mx = fmaxf(mx, __shfl_xor(mx, off, 16));
      float p[4], sum = 0.f;
      for (int ni = 0; ni < 4; ++ni) { p[ni] = __expf(s[ni][r] * scale - mx); sum += p[ni]; }
      for (int off = 1; off < 16; off <<= 1) sum += __shfl_xor(sum, off, 16);
      float inv = 1.0f / sum;
      for (int ni = 0; ni < 4; ++ni)
        Ps[(quad * 4 + r) * 72 + ni * 16 + lanelo] = f2bf(p[ni] * inv);
    }
    __syncthreads();
    bf16x8 p0 = *reinterpret_cast<const bf16x8*>(&Ps[lanelo * 72 + quad * 8]);
    bf16x8 p1 = *reinterpret_cast<const bf16x8*>(&Ps[lanelo * 72 + 32 + quad * 8]);
    f32x4 o0 = __builtin_amdgcn_mfma_f32_16x16x32_bf16(p0, vf0[0], zero, 0, 0, 0);
    o0 = __builtin_amdgcn_mfma_f32_16x16x32_bf16(p1, vf1[0], o0, 0, 0, 0);
    f32x4 o1 = __builtin_amdgcn_mfma_f32_16x16x32_bf16(p0, vf0[1], zero, 0, 0, 0);
    o1 = __builtin_amdgcn_mfma_f32_16x16x32_bf16(p1, vf1[1], o1, 0, 0, 0);
    for (int r = 0; r < 4; ++r) {
      Os[(quad * 4 + r) * 40 + lanelo] = f2bf(o0[r]);
      Os[(quad * 4 + r) * 40 + 16 + lanelo] = f2bf(o1[r]);
    }
    __syncthreads();
    {
      int tok = lane >> 2, part = lane & 3;
      uint4 vv = *reinterpret_cast<const uint4*>(&Os[tok * 40 + part * 8]);
      int gt = mi * 16 + tok;            // token within window == n' low bits
      *reinterpret_cast<uint4*>(attb + (size_t)gt * C_ + part * 8) = vv;
    }
    __syncthreads();
  }
}

// ---------------- K6: output projection + residual (un-permutes pixels) ----------------
// Tile row f maps to global pixel n' = n0 + rho(f), rho(f) = (f&7)|((f>>3)&1)<<6|((f>>4)&7)<<3.
// rho is bijective on 0..127 and makes 16 consecutive lanelo = 16 contiguous image
// pixels (same row of two adjacent windows) => 64B store/residual coalescing kept.
__global__ __launch_bounds__(256, 2) void oproj_gemm(
    const unsigned short* __restrict__ Wo, const unsigned short* __restrict__ attn,
    const float* __restrict__ ob, const float* __restrict__ qin, float* __restrict__ out) {
  __shared__ __align__(16) unsigned short As[128 * 32];
  __shared__ __align__(16) unsigned short Bs[128 * 32];
  int mt = blockIdx.x, nt = blockIdx.y, b = blockIdx.z;
  int m0 = mt * 128, n0 = nt * 128;
  int t = threadIdx.x;
  int wv = t >> 6, lane = t & 63;
  int lanelo = lane & 15, quad = lane >> 4;
  const unsigned short* xb = attn + (size_t)b * HW_ * C_;
  f32x4 acc[4][4];
  for (int i = 0; i < 4; ++i)
    for (int j = 0; j < 4; ++j) acc[i][j] = f32x4{0.f, 0.f, 0.f, 0.f};
  int row_in = lane >> 2;
  int kcol = (lane & 3) * 8;
  int wm = wv & 1, wn = wv >> 1;
  for (int kt = 0; kt < 8; ++kt) {
    int k0 = kt * 32;
    for (int j = 0; j < 2; ++j) {
      int r = wv * 32 + j * 16 + row_in;
      int rp = (r & 7) | (((r >> 3) & 1) << 6) | (((r >> 4) & 7) << 3);
      GL16(Wo + (size_t)(m0 + r) * 256 + k0 + kcol, &As[(wv * 2 + j) * 512]);
      GL16(xb + (size_t)(n0 + rp) * 256 + k0 + kcol, &Bs[(wv * 2 + j) * 512]);
    }
    __syncthreads();
    bf16x8 af[4], bff[4];
    for (int i = 0; i < 4; ++i) {
      af[i]  = *reinterpret_cast<const bf16x8*>(&As[(wm * 64 + i * 16 + lanelo) * 32 + quad * 8]);
      bff[i] = *reinterpret_cast<const bf16x8*>(&Bs[(wn * 64 + i * 16 + lanelo) * 32 + quad * 8]);
    }
    for (int i = 0; i < 4; ++i)
      for (int j = 0; j < 4; ++j)
        acc[i][j] = __builtin_amdgcn_mfma_f32_16x16x32_bf16(af[i], bff[j], acc[i][j], 0, 0, 0);
    __syncthreads();
  }
  const float rs2 = 0.7071067811865476f;
  for (int i = 0; i < 4; ++i) {
    int o_base = m0 + wm * 64 + i * 16 + quad * 4;
    for (int j = 0; j < 4; ++j) {
      int f = wn * 64 + j * 16 + lanelo;
      int fp = (f & 7) | (((f >> 3) & 1) << 6) | (((f >> 4) & 7) << 3);
      int np = n0 + fp;
      int win = np >> 6, tok = np & 63;
      int pix = ((win >> 5) * 8 + (tok >> 3)) * 256 + ((win & 31) * 8) + (tok & 7);
      for (int r = 0; r < 4; ++r) {
        int o = o_base + r;
        size_t off = ((size_t)b * C_ + o) * HW_ + pix;
        out[off] = (acc[i][j][r] + ob[o] + qin[off]) * rs2;
      }
    }
  }
}

extern "C" void kernel_launch(void* const* d_in, const int* in_sizes, int n_in,
                              void* d_out, int out_size, void* d_ws, size_t ws_size,
                              hipStream_t stream) {
  const float* x    = (const float*)d_in[0];
  const float* gn_w = (const float*)d_in[1];
  const float* gn_b = (const float*)d_in[2];
  const float* q_w  = (const float*)d_in[3];
  const float* q_b  = (const float*)d_in[4];
  const float* k_w  = (const float*)d_in[5];
  const float* k_b  = (const float*)d_in[6];
  const float* v_w  = (const float*)d_in[7];
  const float* v_b  = (const float*)d_in[8];
  const float* o_w  = (const float*)d_in[9];
  const float* o_b  = (const float*)d_in[10];
  float* out = (float*)d_out;
  char* ws = (char*)d_ws;

  float* part = (float*)(ws + 0);                         // 8 KiB
  float* A    = (float*)(ws + 8192);                      // 4 KiB
  float* D    = (float*)(ws + 12288);                     // 4 KiB
  unsigned short* Wall = (unsigned short*)(ws + 16384);   // 384 KiB
  unsigned short* Wo   = (unsigned short*)(ws + 16384 + 393216); // 128 KiB
  unsigned short* xn   = (unsigned short*)(ws + ((size_t)1 << 20));                      // 128 MiB
  unsigned short* qkv  = (unsigned short*)(ws + ((size_t)1 << 20) + ((size_t)128 << 20)); // 384 MiB
  unsigned short* attn = xn;   // alias: xn dead after qkv_gemm

  gn_partial<<<dim3(8, 32, 4), 256, 0, stream>>>(x, part);
  gn_finalize<<<dim3(4), 256, 0, stream>>>(part, gn_w, gn_b, A, D);
  pack_weights<<<dim3(1024), 256, 0, stream>>>(q_w, k_w, v_w, o_w, Wall, Wo);
  norm_transpose<<<dim3(1024, 4, 4), 256, 0, stream>>>(x, A, D, xn);
  qkv_gemm<<<dim3(6, 512, 4), 256, 0, stream>>>(Wall, xn, q_b, k_b, v_b, qkv);
  attn_kernel<<<dim3(32768), 64, 0, stream>>>(qkv, attn);
  oproj_gemm<<<dim3(2, 512, 4), 256, 0, stream>>>(Wo, attn, o_b, x, out);
}